// Round 9
// baseline (79.550 us; speedup 1.0000x reference)
//
#include <hip/hip_runtime.h>
#include <hip/hip_bf16.h>

// out = x @ bmat + h*a + (h@q) @ p^T ; M=64, N=K=8192, bmat f32 streamed once.
// Streaming GEMM: wave = 64 rows x 128 cols, dwordx2 loads (512B contiguous
// per instruction), block strip = 1024 cols (4KB per row visit), 32 k-slabs.
// Each wave stages its k-tile into WAVE-PRIVATE transposed LDS ([col][k],
// XOR-swizzled) -> B-frags are single ds_read_b128; no barriers in main loop.
// Depth-2 global register pipeline. Partials bf16 [ks][64][8192] -> combine.

#define HDIM 8192
#define BDIM 64
#define RDIM 4
#define KSPLIT 32
#define KSLAB 256            // HDIM / KSPLIT
#define NTILE (KSLAB / 16)   // 16 k-tiles of 16 rows

typedef short short8 __attribute__((ext_vector_type(8)));
typedef float f32x2 __attribute__((ext_vector_type(2)));
typedef float f32x4 __attribute__((ext_vector_type(4)));
typedef float f32x16 __attribute__((ext_vector_type(16)));
typedef unsigned uint4v __attribute__((ext_vector_type(4)));

__device__ __forceinline__ unsigned f2bf(float f) {
  // round-to-nearest-even f32 -> bf16 (finite inputs); low 16 bits valid
  unsigned u = __float_as_uint(f);
  unsigned r = u + 0x7fffu + ((u >> 16) & 1u);
  return r >> 16;
}

__device__ __forceinline__ float bf2f(unsigned short u) {
  return __uint_as_float(((unsigned)u) << 16);
}

// ---- prep: x row b -> bf16, and hq[b] = h[b] @ q ; one block per row ----
__global__ __launch_bounds__(256)
void prep_hq_kernel(const float* __restrict__ x,
                    const float* __restrict__ h,
                    const float* __restrict__ q,
                    unsigned short* __restrict__ xb,
                    float* __restrict__ hq) {
  const int b = blockIdx.x, t = threadIdx.x;
  {
    const float* xrow = x + (size_t)b * HDIM;
    unsigned short* xo = xb + (size_t)b * HDIM;
#pragma unroll
    for (int i = 0; i < 4; ++i) {
      const int base = (t * 4 + i) * 8;
      f32x4 v0 = *(const f32x4*)(xrow + base);
      f32x4 v1 = *(const f32x4*)(xrow + base + 4);
      union { unsigned short u[8]; short8 s; } o;
#pragma unroll
      for (int e = 0; e < 4; ++e) {
        o.u[e] = (unsigned short)f2bf(v0[e]);
        o.u[4 + e] = (unsigned short)f2bf(v1[e]);
      }
      *(short8*)(xo + base) = o.s;
    }
  }
  const float* hrow = h + (size_t)b * HDIM;
  f32x4 s = {0.f, 0.f, 0.f, 0.f};
  for (int k = t; k < HDIM; k += 256) {
    float hv = hrow[k];
    f32x4 qv = *(const f32x4*)(q + (size_t)k * RDIM);
    s += hv * qv;
  }
  __shared__ f32x4 red[256];
  red[t] = s;
  __syncthreads();
  for (int off = 128; off > 0; off >>= 1) {
    if (t < off) red[t] += red[t + off];
    __syncthreads();
  }
  if (t == 0) *(f32x4*)(hq + (size_t)b * RDIM) = red[0];
}

// ---- main: partial C for one (jg, ks): 64 rows x 1024 cols over K=256 ----
__global__ __launch_bounds__(512, 2)
void dplr_main(const float* __restrict__ bmat,
               const unsigned short* __restrict__ xb,
               unsigned short* __restrict__ part) {
  __shared__ __align__(16) unsigned short xs[BDIM * KSLAB];   // 32 KiB
  __shared__ __align__(16) unsigned short stg[8 * 128 * 16];  // 32 KiB (4KB/wave)

  const int t    = threadIdx.x;
  const int lane = t & 63;
  const int w    = t >> 6;        // 8 waves, side-by-side in columns
  const int c32  = lane & 31;
  const int kh   = lane >> 5;     // k-half of 32x32x16 fragments

  const int jg = blockIdx.x & 7;
  const int ks = blockIdx.x >> 3;
  const int k0 = ks * KSLAB;

  // ---- stage x slab once (64 rows x 256 k), granule g' = g ^ (row&7) ----
  {
    const int row = t >> 3;
    const int g0  = (t & 7) * 4;         // 32 granules/row, 4 per thread
    const unsigned short* src = xb + (size_t)row * HDIM + k0 + g0 * 8;
#pragma unroll
    for (int i = 0; i < 4; ++i) {
      const int g  = row * (KSLAB / 8) + g0 + i;
      const int gs = g ^ (row & 7);
      *(short8*)&xs[gs * 8] = *(const short8*)(src + i * 8);
    }
  }
  __syncthreads();   // the only barrier in this kernel

  const int j0 = jg * 1024 + w * 128;
  const float* b0 = bmat + (size_t)k0 * HDIM + j0 + 2 * lane;

  unsigned short* wbuf = stg + w * (128 * 16);  // wave-private 2048 shorts

  f32x16 acc[2][4];
#pragma unroll
  for (int mt = 0; mt < 2; ++mt)
#pragma unroll
    for (int nt = 0; nt < 4; ++nt)
#pragma unroll
      for (int r = 0; r < 16; ++r) acc[mt][nt][r] = 0.f;

  f32x2 LA[16], LB[16];

  auto issue = [&](int kt, f32x2* L) {
#pragma unroll
    for (int i = 0; i < 16; ++i)
      L[i] = *(const f32x2*)(b0 + (size_t)(kt * 16 + i) * HDIM);
  };

  // transpose-stage one 16-row tile into wave LDS: layout [col][k] bf16,
  // 16B granules: idx = col*2 + h ; phys = idx ^ ((col>>1)&7)
  auto stage = [&](const f32x2* L) {
    unsigned R[16];
#pragma unroll
    for (int i = 0; i < 16; ++i)
      R[i] = f2bf(L[i].x) | (f2bf(L[i].y) << 16);
    unsigned ev[8], od[8];
#pragma unroll
    for (int j = 0; j < 8; ++j) {
      ev[j] = (R[2 * j] & 0xffffu) | (R[2 * j + 1] << 16);
      od[j] = (R[2 * j] >> 16) | (R[2 * j + 1] & 0xffff0000u);
    }
    const int cw0 = 2 * lane;          // wave-local even col
    const int cw1 = cw0 + 1;
    const int s0  = (cw0 >> 1) & 7;    // = lane & 7
    const int s1  = (cw1 >> 1) & 7;
    uint4v v;
    v = (uint4v){ev[0], ev[1], ev[2], ev[3]};
    *(uint4v*)&wbuf[((cw0 * 2 + 0) ^ s0) * 8] = v;
    v = (uint4v){ev[4], ev[5], ev[6], ev[7]};
    *(uint4v*)&wbuf[((cw0 * 2 + 1) ^ s0) * 8] = v;
    v = (uint4v){od[0], od[1], od[2], od[3]};
    *(uint4v*)&wbuf[((cw1 * 2 + 0) ^ s1) * 8] = v;
    v = (uint4v){od[4], od[5], od[6], od[7]};
    *(uint4v*)&wbuf[((cw1 * 2 + 1) ^ s1) * 8] = v;
  };

  auto domfma = [&](int kt) {
#pragma unroll
    for (int nt = 0; nt < 4; ++nt) {
      const int col = nt * 32 + c32;                       // wave-local col
      const int p   = ((col * 2 + kh) ^ ((col >> 1) & 7)) * 8;
      short8 bf = *(const short8*)&wbuf[p];
#pragma unroll
      for (int mt = 0; mt < 2; ++mt) {
        const int row = mt * 32 + c32;
        const int g   = row * (KSLAB / 8) + kt * 2 + kh;
        const int gs  = g ^ (row & 7);
        short8 af = *(const short8*)&xs[gs * 8];
        acc[mt][nt] =
            __builtin_amdgcn_mfma_f32_32x32x16_bf16(af, bf, acc[mt][nt], 0, 0, 0);
      }
    }
  };

  issue(0, LA);
  issue(1, LB);
  for (int kt = 0; kt < NTILE; kt += 2) {
    stage(LA);                               // waits only on LA's 16 loads
    if (kt + 2 < NTILE) issue(kt + 2, LA);
    domfma(kt);
    stage(LB);
    if (kt + 3 < NTILE) issue(kt + 3, LB);
    domfma(kt + 1);
  }

  // partial write (bf16): part[ks][row][j]
  // C/D 32x32 layout: col = lane&31, row = (reg&3) + 8*(reg>>2) + 4*kh
  unsigned short* pb = part + (size_t)ks * BDIM * HDIM;
#pragma unroll
  for (int mt = 0; mt < 2; ++mt)
#pragma unroll
    for (int nt = 0; nt < 4; ++nt)
#pragma unroll
      for (int reg = 0; reg < 16; ++reg) {
        const int row = mt * 32 + (reg & 3) + 8 * (reg >> 2) + 4 * kh;
        const int col = j0 + nt * 32 + c32;
        pb[(size_t)row * HDIM + col] = (unsigned short)f2bf(acc[mt][nt][reg]);
      }
}

// ---- combine: out = sum_ks part + h*a + hq @ p^T ----
__global__ __launch_bounds__(256)
void combine_kernel(const unsigned short* __restrict__ part,
                    const float* __restrict__ h,
                    const float* __restrict__ adiag,
                    const float* __restrict__ pvec,
                    const float* __restrict__ hq,
                    float* __restrict__ out) {
  const int tid  = blockIdx.x * 256 + threadIdx.x;
  const int base = tid * 8;            // flat into [64][8192]
  const int row  = base >> 13;
  const int j    = base & 8191;

  float s[8];
#pragma unroll
  for (int e = 0; e < 8; ++e) s[e] = 0.f;
  const unsigned short* pp = part + (size_t)row * HDIM + j;
#pragma unroll
  for (int ks = 0; ks < KSPLIT; ++ks) {
    union { unsigned short u[8]; short8 v; } pv;
    pv.v = *(const short8*)(pp + (size_t)ks * BDIM * HDIM);
#pragma unroll
    for (int e = 0; e < 8; ++e) s[e] += bf2f(pv.u[e]);
  }
  const f32x4 hv0 = *(const f32x4*)(h + (size_t)row * HDIM + j);
  const f32x4 hv1 = *(const f32x4*)(h + (size_t)row * HDIM + j + 4);
  const f32x4 a0  = *(const f32x4*)(adiag + j);
  const f32x4 a1  = *(const f32x4*)(adiag + j + 4);
  const f32x4 hqv = *(const f32x4*)(hq + (size_t)row * RDIM);

  float res[8];
#pragma unroll
  for (int e = 0; e < 4; ++e) {
    const f32x4 pv = *(const f32x4*)(pvec + (size_t)(j + e) * RDIM);
    res[e] = s[e] + hv0[e] * a0[e] +
             hqv[0] * pv[0] + hqv[1] * pv[1] + hqv[2] * pv[2] + hqv[3] * pv[3];
  }
#pragma unroll
  for (int e = 0; e < 4; ++e) {
    const f32x4 pv = *(const f32x4*)(pvec + (size_t)(j + 4 + e) * RDIM);
    res[4 + e] = s[4 + e] + hv1[e] * a1[e] +
                 hqv[0] * pv[0] + hqv[1] * pv[1] + hqv[2] * pv[2] + hqv[3] * pv[3];
  }
  f32x4 o0 = {res[0], res[1], res[2], res[3]};
  f32x4 o1 = {res[4], res[5], res[6], res[7]};
  *(f32x4*)(out + (size_t)row * HDIM + j) = o0;
  *(f32x4*)(out + (size_t)row * HDIM + j + 4) = o1;
}

extern "C" void kernel_launch(void* const* d_in, const int* in_sizes, int n_in,
                              void* d_out, int out_size, void* d_ws, size_t ws_size,
                              hipStream_t stream) {
  const float* h     = (const float*)d_in[0];
  const float* x     = (const float*)d_in[1];
  const float* adiag = (const float*)d_in[2];
  const float* pvec  = (const float*)d_in[3];
  const float* qvec  = (const float*)d_in[4];
  const float* bmat  = (const float*)d_in[5];
  float* out = (float*)d_out;

  unsigned short* xb = (unsigned short*)d_ws;                           // 1 MiB
  float* hqbuf = (float*)((char*)d_ws + ((size_t)1 << 20));             // 1 KiB
  unsigned short* part = (unsigned short*)((char*)d_ws + ((size_t)2 << 20));  // 32 MiB

  prep_hq_kernel<<<BDIM, 256, 0, stream>>>(x, h, qvec, xb, hqbuf);
  dplr_main<<<KSPLIT * 8, 512, 0, stream>>>(bmat, xb, part);
  combine_kernel<<<(BDIM * HDIM / 8) / 256, 256, 0, stream>>>(part, h, adiag, pvec, hqbuf, out);
}

// Round 10
// 73.533 us; speedup vs baseline: 1.0818x; 1.0818x over previous
//
#include <hip/hip_runtime.h>
#include <hip/hip_bf16.h>

// out = x @ bmat + h*a + (h@q) @ p^T ; M=64, N=K=8192, bmat f32 streamed once.
// Barrier-free streaming GEMM (R8 structure) + line-MLP boost:
//  - dwordx2 loads, column-permuted fragments (lane c32 <-> cols 2*c32+{0,1});
//    k-half split via address (+kh*8 rows) -> no cross-lane ops at all.
//  - depth-4 register pipeline: consume leaves 48 instrs (192 lines) in
//    flight per wave (legal vmcnt<=63), ~1536 lines/CU vs R8's ~512.
// Grid/strips/partials identical to R8. Partials bf16 [ks][64][8192].

#define HDIM 8192
#define BDIM 64
#define RDIM 4
#define KSPLIT 16
#define KSLAB 512            // HDIM / KSPLIT
#define NKTILE (KSLAB / 32)  // 16 tiles of 32 k

typedef short short8 __attribute__((ext_vector_type(8)));
typedef float f32x2 __attribute__((ext_vector_type(2)));
typedef float f32x4 __attribute__((ext_vector_type(4)));
typedef float f32x16 __attribute__((ext_vector_type(16)));

__device__ __forceinline__ unsigned f2bf(float f) {
  // round-to-nearest-even f32 -> bf16 (finite inputs); low 16 bits valid
  unsigned u = __float_as_uint(f);
  unsigned r = u + 0x7fffu + ((u >> 16) & 1u);
  return r >> 16;
}

__device__ __forceinline__ float bf2f(unsigned short u) {
  return __uint_as_float(((unsigned)u) << 16);
}

// ---- prep: x row b -> bf16, and hq[b] = h[b] @ q ; one block per row ----
__global__ __launch_bounds__(256)
void prep_hq_kernel(const float* __restrict__ x,
                    const float* __restrict__ h,
                    const float* __restrict__ q,
                    unsigned short* __restrict__ xb,
                    float* __restrict__ hq) {
  const int b = blockIdx.x, t = threadIdx.x;
  {
    const float* xrow = x + (size_t)b * HDIM;
    unsigned short* xo = xb + (size_t)b * HDIM;
#pragma unroll
    for (int i = 0; i < 4; ++i) {
      const int base = (t * 4 + i) * 8;
      f32x4 v0 = *(const f32x4*)(xrow + base);
      f32x4 v1 = *(const f32x4*)(xrow + base + 4);
      union { unsigned short u[8]; short8 s; } o;
#pragma unroll
      for (int e = 0; e < 4; ++e) {
        o.u[e] = (unsigned short)f2bf(v0[e]);
        o.u[4 + e] = (unsigned short)f2bf(v1[e]);
      }
      *(short8*)(xo + base) = o.s;
    }
  }
  const float* hrow = h + (size_t)b * HDIM;
  f32x4 s = {0.f, 0.f, 0.f, 0.f};
  for (int k = t; k < HDIM; k += 256) {
    float hv = hrow[k];
    f32x4 qv = *(const f32x4*)(q + (size_t)k * RDIM);
    s += hv * qv;
  }
  __shared__ f32x4 red[256];
  red[t] = s;
  __syncthreads();
  for (int off = 128; off > 0; off >>= 1) {
    if (t < off) red[t] += red[t + off];
    __syncthreads();
  }
  if (t == 0) *(f32x4*)(hq + (size_t)b * RDIM) = red[0];
}

// ---- main: partial C for one (jg, ks): 64 rows x 512 cols over K=512 ----
// x-LDS: 64 rows x 512 k bf16, 16B granules; phys granule g' = g ^ (row&7).
__global__ __launch_bounds__(512, 2)
void dplr_main(const float* __restrict__ bmat,
               const unsigned short* __restrict__ xb,
               unsigned short* __restrict__ part) {
  __shared__ __align__(16) unsigned short xs[BDIM * KSLAB];  // 64 KiB

  const int t    = threadIdx.x;
  const int lane = t & 63;
  const int w    = t >> 6;        // 8 waves, wave w owns cols j0..j0+63
  const int c32  = lane & 31;
  const int kh   = lane >> 5;     // k-half, handled purely in the address

  const int jg = blockIdx.x & 15;
  const int ks = blockIdx.x >> 4;
  const int k0 = ks * KSLAB;

  // ---- stage x slab once (rows 0..63, k in [k0, k0+512)) ----
  {
    const int row = t >> 3;
    const int g0  = (t & 7) * 8;         // 64 granules/row, 8 per thread
    const unsigned short* src = xb + (size_t)row * HDIM + k0 + g0 * 8;
#pragma unroll
    for (int i = 0; i < 8; ++i) {
      const int g  = row * (KSLAB / 8) + g0 + i;
      const int gs = g ^ (row & 7);
      *(short8*)&xs[gs * 8] = *(const short8*)(src + i * 8);
    }
  }
  __syncthreads();   // the only barrier in this kernel

  const int j0 = jg * 512 + w * 64;
  // lane (c32, kh) loads cols j0+2*c32 .. +1 at rows (k + kh*8 + i)
  const float* b0 = bmat + (size_t)(k0 + kh * 8) * HDIM + j0 + 2 * c32;

  f32x16 acc[2][2];   // [mt][n], compile-time indexed after unroll
#pragma unroll
  for (int mt = 0; mt < 2; ++mt)
#pragma unroll
    for (int n = 0; n < 2; ++n)
#pragma unroll
      for (int r = 0; r < 16; ++r) acc[mt][n][r] = 0.f;

  f32x2 LA[16], LB[16], LC[16], LD[16];  // 4-deep, 16 dwordx2 per tile

  auto issue = [&](int kt, f32x2* L) {
#pragma unroll
    for (int s = 0; s < 2; ++s)
#pragma unroll
      for (int i = 0; i < 8; ++i)
        L[s * 8 + i] = *(const f32x2*)(b0 + (size_t)(kt * 32 + s * 16 + i) * HDIM);
  };

  auto conv_mfma = [&](int kt, const f32x2* L) {
#pragma unroll
    for (int s = 0; s < 2; ++s) {        // two K=16 steps
      union { unsigned u[4]; short8 v; } bf0, bf1;
#pragma unroll
      for (int j = 0; j < 4; ++j) {
        const f32x2 a = L[s * 8 + 2 * j];
        const f32x2 b = L[s * 8 + 2 * j + 1];
        bf0.u[j] = f2bf(a.x) | (f2bf(b.x) << 16);   // col 2*c32+0, k 2j,2j+1
        bf1.u[j] = f2bf(a.y) | (f2bf(b.y) << 16);   // col 2*c32+1
      }
#pragma unroll
      for (int mt = 0; mt < 2; ++mt) {
        const int row = mt * 32 + c32;
        const int g   = row * (KSLAB / 8) + kt * 4 + s * 2 + kh;
        const int gs  = g ^ (row & 7);
        short8 af = *(const short8*)&xs[gs * 8];
        acc[mt][0] = __builtin_amdgcn_mfma_f32_32x32x16_bf16(af, bf0.v, acc[mt][0], 0, 0, 0);
        acc[mt][1] = __builtin_amdgcn_mfma_f32_32x32x16_bf16(af, bf1.v, acc[mt][1], 0, 0, 0);
      }
    }
  };

  issue(0, LA);
  issue(1, LB);
  issue(2, LC);
  issue(3, LD);
  for (int kt = 0; kt < NKTILE; kt += 4) {
    conv_mfma(kt, LA);
    if (kt + 4 < NKTILE) issue(kt + 4, LA);
    conv_mfma(kt + 1, LB);
    if (kt + 5 < NKTILE) issue(kt + 5, LB);
    conv_mfma(kt + 2, LC);
    if (kt + 6 < NKTILE) issue(kt + 6, LC);
    conv_mfma(kt + 3, LD);
    if (kt + 7 < NKTILE) issue(kt + 7, LD);
  }

  // partial write (bf16): part[ks][row][j]
  // C/D 32x32 layout: fragment col slot = lane&31 -> real col j0+2*c32+n;
  // row = (reg&3) + 8*(reg>>2) + 4*kh
  unsigned short* pb = part + (size_t)ks * BDIM * HDIM;
#pragma unroll
  for (int mt = 0; mt < 2; ++mt)
#pragma unroll
    for (int n = 0; n < 2; ++n)
#pragma unroll
      for (int reg = 0; reg < 16; ++reg) {
        const int row = mt * 32 + (reg & 3) + 8 * (reg >> 2) + 4 * kh;
        const int col = j0 + 2 * c32 + n;
        pb[(size_t)row * HDIM + col] = (unsigned short)f2bf(acc[mt][n][reg]);
      }
}

// ---- combine: out = sum_ks part + h*a + hq @ p^T ----
__global__ __launch_bounds__(256)
void combine_kernel(const unsigned short* __restrict__ part,
                    const float* __restrict__ h,
                    const float* __restrict__ adiag,
                    const float* __restrict__ pvec,
                    const float* __restrict__ hq,
                    float* __restrict__ out) {
  const int tid  = blockIdx.x * 256 + threadIdx.x;
  const int base = tid * 8;            // flat into [64][8192]
  const int row  = base >> 13;
  const int j    = base & 8191;

  float s[8];
#pragma unroll
  for (int e = 0; e < 8; ++e) s[e] = 0.f;
  const unsigned short* pp = part + (size_t)row * HDIM + j;
#pragma unroll
  for (int ks = 0; ks < KSPLIT; ++ks) {
    union { unsigned short u[8]; short8 v; } pv;
    pv.v = *(const short8*)(pp + (size_t)ks * BDIM * HDIM);
#pragma unroll
    for (int e = 0; e < 8; ++e) s[e] += bf2f(pv.u[e]);
  }
  const f32x4 hv0 = *(const f32x4*)(h + (size_t)row * HDIM + j);
  const f32x4 hv1 = *(const f32x4*)(h + (size_t)row * HDIM + j + 4);
  const f32x4 a0  = *(const f32x4*)(adiag + j);
  const f32x4 a1  = *(const f32x4*)(adiag + j + 4);
  const f32x4 hqv = *(const f32x4*)(hq + (size_t)row * RDIM);

  float res[8];
#pragma unroll
  for (int e = 0; e < 4; ++e) {
    const f32x4 pv = *(const f32x4*)(pvec + (size_t)(j + e) * RDIM);
    res[e] = s[e] + hv0[e] * a0[e] +
             hqv[0] * pv[0] + hqv[1] * pv[1] + hqv[2] * pv[2] + hqv[3] * pv[3];
  }
#pragma unroll
  for (int e = 0; e < 4; ++e) {
    const f32x4 pv = *(const f32x4*)(pvec + (size_t)(j + 4 + e) * RDIM);
    res[4 + e] = s[4 + e] + hv1[e] * a1[e] +
                 hqv[0] * pv[0] + hqv[1] * pv[1] + hqv[2] * pv[2] + hqv[3] * pv[3];
  }
  f32x4 o0 = {res[0], res[1], res[2], res[3]};
  f32x4 o1 = {res[4], res[5], res[6], res[7]};
  *(f32x4*)(out + (size_t)row * HDIM + j) = o0;
  *(f32x4*)(out + (size_t)row * HDIM + j + 4) = o1;
}

extern "C" void kernel_launch(void* const* d_in, const int* in_sizes, int n_in,
                              void* d_out, int out_size, void* d_ws, size_t ws_size,
                              hipStream_t stream) {
  const float* h     = (const float*)d_in[0];
  const float* x     = (const float*)d_in[1];
  const float* adiag = (const float*)d_in[2];
  const float* pvec  = (const float*)d_in[3];
  const float* qvec  = (const float*)d_in[4];
  const float* bmat  = (const float*)d_in[5];
  float* out = (float*)d_out;

  unsigned short* xb = (unsigned short*)d_ws;                           // 1 MiB
  float* hqbuf = (float*)((char*)d_ws + ((size_t)1 << 20));             // 1 KiB
  unsigned short* part = (unsigned short*)((char*)d_ws + ((size_t)2 << 20));  // 16 MiB

  prep_hq_kernel<<<BDIM, 256, 0, stream>>>(x, h, qvec, xb, hqbuf);
  dplr_main<<<KSPLIT * 16, 512, 0, stream>>>(bmat, xb, part);
  combine_kernel<<<(BDIM * HDIM / 8) / 256, 256, 0, stream>>>(part, h, adiag, pvec, hqbuf, out);
}